// Round 1
// baseline (1208.490 us; speedup 1.0000x reference)
//
#include <hip/hip_runtime.h>

// ---------------------------------------------------------------------------
// MHA forward: out = (softmax((XWq+bq)(KWk+bk)^T / 8) (CWv+bv)) Wo + bo
// Outputs: out [8,1024,1024] fp32, attn [8,16,1024,1024] fp32 (concatenated).
// All matmuls via v_mfma_f32_16x16x32_f16 (fp16 inputs, fp32 accum).
// ---------------------------------------------------------------------------

typedef _Float16 half8 __attribute__((ext_vector_type(8)));
typedef float f32x4 __attribute__((ext_vector_type(4)));

#define B_SZ 8
#define NH 16
#define DKK 64
#define LSEQ 1024
#define DM 1024

// ---------------- weight transpose+convert: W[k][n] fp32 -> Wt[n][k] fp16 ---
__global__ void prep_w(const float* __restrict__ W, _Float16* __restrict__ Wt) {
    __shared__ float tile[32][33];
    int bx = blockIdx.x * 32;  // k base
    int by = blockIdx.y * 32;  // n base
    int tx = threadIdx.x;      // 0..31
    int ty = threadIdx.y;      // 0..7
#pragma unroll
    for (int i = 0; i < 4; i++) {
        int k = bx + ty + i * 8;
        tile[ty + i * 8][tx] = W[(size_t)k * DM + by + tx];
    }
    __syncthreads();
#pragma unroll
    for (int i = 0; i < 4; i++) {
        int n = by + ty + i * 8;
        Wt[(size_t)n * DM + bx + tx] = (_Float16)tile[tx][ty + i * 8];
    }
}

// ---------------- GEMM: C = A @ Wt^T + bias --------------------------------
// MODE 0: A fp32 [8192][1024]; C fp16 head-split [B,H,L,64], val=(acc+b)*scale
// MODE 1: A fp16 [8192][1024]; C fp32 row-major [8192][1024]
// BM=BN=128, BK=32, 256 threads (4 waves, each 64x64 = 4x4 16x16 frags)
template <int MODE>
__global__ __launch_bounds__(256) void gemm_proj(
    const void* __restrict__ Ap, const _Float16* __restrict__ Wt,
    const float* __restrict__ bias, void* __restrict__ Cp, float scale) {
    __shared__ _Float16 lds_a[128][40];
    __shared__ _Float16 lds_b[128][40];
    int m0 = blockIdx.x * 128, n0 = blockIdx.y * 128;
    int t = threadIdx.x;
    int r = t >> 1, cb = (t & 1) * 16;
    int w = t >> 6, lane = t & 63, lr = lane & 15, lg = lane >> 4;
    int wm = (w >> 1) * 64, wn = (w & 1) * 64;
    f32x4 acc[4][4] = {};

    for (int kt = 0; kt < 32; kt++) {
        int k0 = kt * 32;
        __syncthreads();
        // stage A tile -> lds_a[r][cb..cb+15]
        if constexpr (MODE == 0) {
            const float* A = (const float*)Ap + (size_t)(m0 + r) * DM + k0 + cb;
            _Float16 tmp[16] __attribute__((aligned(16)));
#pragma unroll
            for (int i = 0; i < 16; i += 4) {
                float4 f = *(const float4*)(A + i);
                tmp[i] = (_Float16)f.x; tmp[i + 1] = (_Float16)f.y;
                tmp[i + 2] = (_Float16)f.z; tmp[i + 3] = (_Float16)f.w;
            }
            *(half8*)&lds_a[r][cb] = *(half8*)&tmp[0];
            *(half8*)&lds_a[r][cb + 8] = *(half8*)&tmp[8];
        } else {
            const _Float16* A = (const _Float16*)Ap + (size_t)(m0 + r) * DM + k0 + cb;
            *(half8*)&lds_a[r][cb] = *(const half8*)A;
            *(half8*)&lds_a[r][cb + 8] = *(const half8*)(A + 8);
        }
        // stage B tile (Wt already fp16 [n][k])
        const _Float16* Bs = Wt + (size_t)(n0 + r) * DM + k0 + cb;
        *(half8*)&lds_b[r][cb] = *(const half8*)Bs;
        *(half8*)&lds_b[r][cb + 8] = *(const half8*)(Bs + 8);
        __syncthreads();

        half8 af[4], bf[4];
#pragma unroll
        for (int mi = 0; mi < 4; mi++)
            af[mi] = *(const half8*)&lds_a[wm + mi * 16 + lr][lg * 8];
#pragma unroll
        for (int ni = 0; ni < 4; ni++)
            bf[ni] = *(const half8*)&lds_b[wn + ni * 16 + lr][lg * 8];
#pragma unroll
        for (int mi = 0; mi < 4; mi++)
#pragma unroll
            for (int ni = 0; ni < 4; ni++)
                acc[mi][ni] = __builtin_amdgcn_mfma_f32_16x16x32_f16(
                    af[mi], bf[ni], acc[mi][ni], 0, 0, 0);
    }

    // epilogue: C/D layout col = lane&15, row = (lane>>4)*4 + j
#pragma unroll
    for (int mi = 0; mi < 4; mi++) {
#pragma unroll
        for (int ni = 0; ni < 4; ni++) {
            int n = n0 + wn + ni * 16 + lr;
            float bv = bias[n];
            int mbase = m0 + wm + mi * 16 + lg * 4;
#pragma unroll
            for (int j = 0; j < 4; j++) {
                float val = (acc[mi][ni][j] + bv) * scale;
                int m = mbase + j;
                if constexpr (MODE == 1) {
                    ((float*)Cp)[(size_t)m * DM + n] = val;
                } else {
                    int b = m >> 10, l = m & 1023, hh = n >> 6, d = n & 63;
                    ((_Float16*)Cp)[(((size_t)(b * NH + hh)) << 16) + l * DKK + d] =
                        (_Float16)val;
                }
            }
        }
    }
}

// ---------------- V transpose per head: [bh][l][d] -> [bh][d][l] -----------
__global__ __launch_bounds__(256) void transpose_v(
    const _Float16* __restrict__ Vin, _Float16* __restrict__ Vt) {
    __shared__ _Float16 tile[64][72];
    int bh = blockIdx.y;
    int l0 = blockIdx.x * 64;
    int t = threadIdx.x;
    const _Float16* src = Vin + ((size_t)bh << 16) + (size_t)l0 * DKK;
    int r = t >> 2, c0 = (t & 3) * 16;
    *(half8*)&tile[r][c0] = *(const half8*)&src[r * DKK + c0];
    *(half8*)&tile[r][c0 + 8] = *(const half8*)&src[r * DKK + c0 + 8];
    __syncthreads();
    int d = t >> 2, lp = (t & 3) * 16;
    _Float16 tmp[16] __attribute__((aligned(16)));
#pragma unroll
    for (int i = 0; i < 16; i++) tmp[i] = tile[lp + i][d];
    _Float16* dst = Vt + ((size_t)bh << 16) + (size_t)d * LSEQ + l0 + lp;
    *(half8*)&dst[0] = *(half8*)&tmp[0];
    *(half8*)&dst[8] = *(half8*)&tmp[8];
}

// ---------------- attention: S=QK^T (Q pre-scaled), softmax, attn out, PV ---
// grid (16 q-tiles, 128 bh), 256 thr = 4 waves, wave handles 16 q rows.
__global__ __launch_bounds__(256) void attn_kernel(
    const _Float16* __restrict__ Q, const _Float16* __restrict__ K,
    const _Float16* __restrict__ Vt, float* __restrict__ attn,
    _Float16* __restrict__ ctxo) {
    __shared__ _Float16 P_lds[4][16][40];
    int bh = blockIdx.y;
    int b = bh >> 4, h = bh & 15;
    int w = threadIdx.x >> 6, lane = threadIdx.x & 63;
    int lr = lane & 15, lg = lane >> 4;
    int q0 = blockIdx.x * 64 + w * 16;
    const _Float16* Qb = Q + ((size_t)bh << 16);
    const _Float16* Kb = K + ((size_t)bh << 16);
    const _Float16* Vb = Vt + ((size_t)bh << 16);

    half8 qf0 = *(const half8*)&Qb[(q0 + lr) * DKK + lg * 8];
    half8 qf1 = *(const half8*)&Qb[(q0 + lr) * DKK + 32 + lg * 8];

    // ---- pass 1: row max ----
    float m[4] = {-3e30f, -3e30f, -3e30f, -3e30f};
    for (int t = 0; t < 64; t++) {
        const _Float16* Kp = &Kb[(t * 16 + lr) * DKK + lg * 8];
        half8 kf0 = *(const half8*)Kp;
        half8 kf1 = *(const half8*)(Kp + 32);
        f32x4 s = {0.f, 0.f, 0.f, 0.f};
        s = __builtin_amdgcn_mfma_f32_16x16x32_f16(qf0, kf0, s, 0, 0, 0);
        s = __builtin_amdgcn_mfma_f32_16x16x32_f16(qf1, kf1, s, 0, 0, 0);
#pragma unroll
        for (int j = 0; j < 4; j++) m[j] = fmaxf(m[j], s[j]);
    }
#pragma unroll
    for (int j = 0; j < 4; j++) {
        float v = m[j];
#pragma unroll
        for (int off = 1; off < 16; off <<= 1) v = fmaxf(v, __shfl_xor(v, off, 16));
        m[j] = v;
    }

    // ---- pass 2: row sum of exp ----
    float sl[4] = {0.f, 0.f, 0.f, 0.f};
    for (int t = 0; t < 64; t++) {
        const _Float16* Kp = &Kb[(t * 16 + lr) * DKK + lg * 8];
        half8 kf0 = *(const half8*)Kp;
        half8 kf1 = *(const half8*)(Kp + 32);
        f32x4 s = {0.f, 0.f, 0.f, 0.f};
        s = __builtin_amdgcn_mfma_f32_16x16x32_f16(qf0, kf0, s, 0, 0, 0);
        s = __builtin_amdgcn_mfma_f32_16x16x32_f16(qf1, kf1, s, 0, 0, 0);
#pragma unroll
        for (int j = 0; j < 4; j++) sl[j] += __expf(s[j] - m[j]);
    }
    float inv[4];
#pragma unroll
    for (int j = 0; j < 4; j++) {
        float v = sl[j];
#pragma unroll
        for (int off = 1; off < 16; off <<= 1) v += __shfl_xor(v, off, 16);
        inv[j] = 1.0f / v;
    }

    // ---- pass 3: probs -> attn out (fp32) + LDS -> PV MFMA ----
    f32x4 cacc[4] = {};
    for (int pr = 0; pr < 32; pr++) {
#pragma unroll
        for (int sub = 0; sub < 2; sub++) {
            int t = pr * 2 + sub;
            const _Float16* Kp = &Kb[(t * 16 + lr) * DKK + lg * 8];
            half8 kf0 = *(const half8*)Kp;
            half8 kf1 = *(const half8*)(Kp + 32);
            f32x4 s = {0.f, 0.f, 0.f, 0.f};
            s = __builtin_amdgcn_mfma_f32_16x16x32_f16(qf0, kf0, s, 0, 0, 0);
            s = __builtin_amdgcn_mfma_f32_16x16x32_f16(qf1, kf1, s, 0, 0, 0);
#pragma unroll
            for (int j = 0; j < 4; j++) {
                float p = __expf(s[j] - m[j]) * inv[j];
                attn[((size_t)bh << 20) + ((size_t)(q0 + lg * 4 + j) << 10) +
                     t * 16 + lr] = p;
                P_lds[w][lg * 4 + j][sub * 16 + lr] = (_Float16)p;
            }
        }
        __syncthreads();
        half8 pf = *(const half8*)&P_lds[w][lr][lg * 8];
#pragma unroll
        for (int dt = 0; dt < 4; dt++) {
            half8 vf = *(const half8*)&Vb[(dt * 16 + lr) * LSEQ + pr * 32 + lg * 8];
            cacc[dt] = __builtin_amdgcn_mfma_f32_16x16x32_f16(pf, vf, cacc[dt], 0, 0, 0);
        }
        __syncthreads();
    }

    // ctx out, merged-head layout [b*1024+q][h*64+d] fp16
#pragma unroll
    for (int dt = 0; dt < 4; dt++) {
#pragma unroll
        for (int j = 0; j < 4; j++) {
            int q = q0 + lg * 4 + j;
            ctxo[(size_t)(b * LSEQ + q) * DM + h * DKK + dt * 16 + lr] =
                (_Float16)cacc[dt][j];
        }
    }
}

// ---------------------------------------------------------------------------
extern "C" void kernel_launch(void* const* d_in, const int* in_sizes, int n_in,
                              void* d_out, int out_size, void* d_ws, size_t ws_size,
                              hipStream_t stream) {
    const float* hidden = (const float*)d_in[0];
    const float* key    = (const float*)d_in[1];
    const float* ctxv   = (const float*)d_in[2];
    const float* Wq = (const float*)d_in[3];  const float* bq = (const float*)d_in[4];
    const float* Wk = (const float*)d_in[5];  const float* bk = (const float*)d_in[6];
    const float* Wv = (const float*)d_in[7];  const float* bv = (const float*)d_in[8];
    const float* Wo = (const float*)d_in[9];  const float* bo = (const float*)d_in[10];

    float* out  = (float*)d_out;
    float* attn = out + (size_t)B_SZ * LSEQ * DM;  // 8,388,608 floats in

    char* ws = (char*)d_ws;
    const size_t MB = 1024 * 1024;
    _Float16* WtQ  = (_Float16*)(ws + 0 * MB);
    _Float16* WtK  = (_Float16*)(ws + 2 * MB);
    _Float16* WtV  = (_Float16*)(ws + 4 * MB);
    _Float16* WtO  = (_Float16*)(ws + 6 * MB);
    _Float16* Qw   = (_Float16*)(ws + 8 * MB);   // [B,H,L,64] fp16, 16MB
    _Float16* Kw   = (_Float16*)(ws + 24 * MB);  // 16MB
    _Float16* Vtr  = (_Float16*)(ws + 40 * MB);  // [B,H,64,L] 16MB
    _Float16* Vtmp = (_Float16*)(ws + 56 * MB);  // 16MB, reused as ctx after transpose
    _Float16* ctxw = Vtmp;

    dim3 tb(32, 8);
    prep_w<<<dim3(32, 32), tb, 0, stream>>>(Wq, WtQ);
    prep_w<<<dim3(32, 32), tb, 0, stream>>>(Wk, WtK);
    prep_w<<<dim3(32, 32), tb, 0, stream>>>(Wv, WtV);
    prep_w<<<dim3(32, 32), tb, 0, stream>>>(Wo, WtO);

    dim3 gg(64, 8);
    gemm_proj<0><<<gg, 256, 0, stream>>>(hidden, WtQ, bq, Qw, 0.125f);
    gemm_proj<0><<<gg, 256, 0, stream>>>(key,    WtK, bk, Kw, 1.0f);
    gemm_proj<0><<<gg, 256, 0, stream>>>(ctxv,   WtV, bv, Vtmp, 1.0f);

    transpose_v<<<dim3(16, 128), 256, 0, stream>>>(Vtmp, Vtr);

    attn_kernel<<<dim3(16, 128), 256, 0, stream>>>(Qw, Kw, Vtr, attn, ctxw);

    gemm_proj<1><<<gg, 256, 0, stream>>>(ctxw, WtO, bo, out, 1.0f);
}